// Round 8
// baseline (484.676 us; speedup 1.0000x reference)
//
#include <hip/hip_runtime.h>
#include <math.h>

#define DD 128
#define COUT 40
#define BN_EPS 1e-5f
#define L2_EPS 1e-12f

typedef __attribute__((ext_vector_type(8))) short bf16x8;
typedef __attribute__((ext_vector_type(4))) float f32x4;

static __device__ inline unsigned short f2bf(float f) {
    unsigned int x = __float_as_uint(f);
    unsigned int r = (x + 0x7FFFu + ((x >> 16) & 1u)) >> 16;   // RNE
    return (unsigned short)r;
}
static __device__ inline float bf2f(unsigned short u) {
    return __uint_as_float(((unsigned int)u) << 16);
}

// ---------------- setup kernels ----------------

// One dispatch: repack W1/W2/W3 (blocks 0..23), Wout (24..26), zero stats (27),
// zero deg+fill (28..). W in: [k][n] fp32 row-major; out: bf16 B-fragment order.
__global__ void k_prep(const float* __restrict__ W1, const float* __restrict__ W2,
                       const float* __restrict__ W3, const float* __restrict__ Wout,
                       unsigned short* __restrict__ wb,    // 3 * 16384
                       unsigned short* __restrict__ wob,   // 6144
                       float* __restrict__ stats,          // 768
                       int* __restrict__ zbase, int zn) {  // deg+fill, zn ints (mult of 8)
    int b = blockIdx.x;
    if (b < 24) {
        int wi = b >> 3;
        const float* W = (wi == 0) ? W1 : (wi == 1) ? W2 : W3;
        unsigned short* out = wb + wi * 16384;
        int idx = (b & 7) * 256 + threadIdx.x;      // 0..2047
        int kc = idx >> 9;
        int cc = (idx >> 6) & 7;
        int lane = idx & 63;
        int n = cc * 16 + (lane & 15);
        int kb = kc * 32 + (lane >> 4) * 8;
        unsigned short tmp[8];
#pragma unroll
        for (int j = 0; j < 8; j++) tmp[j] = f2bf(W[(size_t)(kb + j) * DD + n]);
        *(uint4*)&out[(size_t)idx * 8] = *(const uint4*)tmp;
    } else if (b < 27) {
        int idx = (b - 24) * 256 + threadIdx.x;     // 0..767
        int kc = idx / 192;
        int rem = idx % 192;
        int cc = rem >> 6;
        int lane = rem & 63;
        int n = cc * 16 + (lane & 15);
        int kb = kc * 32 + (lane >> 4) * 8;
        unsigned short tmp[8];
#pragma unroll
        for (int j = 0; j < 8; j++)
            tmp[j] = (n < COUT) ? f2bf(Wout[(size_t)(kb + j) * COUT + n]) : 0;
        *(uint4*)&wob[(size_t)idx * 8] = *(const uint4*)tmp;
    } else if (b == 27) {
        stats[threadIdx.x] = 0.f;
        stats[256 + threadIdx.x] = 0.f;
        stats[512 + threadIdx.x] = 0.f;
    } else {
        int idx = (b - 28) * 2048 + threadIdx.x * 8;
        if (idx + 8 <= zn) {
            *(int4*)&zbase[idx] = make_int4(0, 0, 0, 0);
            *(int4*)&zbase[idx + 4] = make_int4(0, 0, 0, 0);
        }
    }
}

__global__ void k_hist(const int* ei, int E, int* deg) {
    int i = blockIdx.x * blockDim.x + threadIdx.x;
    if (i < E) atomicAdd(&deg[ei[E + i]], 1);   // dst = ei[E+i]
}

// scan over n+1 entries of (deg[i]+1) [0 for i==n]; also emits dinv = rsqrt(deg+1)
__global__ void k_scan_a(const int* deg, int* row_ptr, int* bsum, float* dinv, int n) {
    __shared__ int s[256];
    int t = threadIdx.x;
    int idx = blockIdx.x * 256 + t;
    int v = (idx < n) ? deg[idx] + 1 : 0;
    if (idx < n) dinv[idx] = rsqrtf((float)v);
    s[t] = v; __syncthreads();
    for (int off = 1; off < 256; off <<= 1) {
        int x = (t >= off) ? s[t - off] : 0;
        __syncthreads(); s[t] += x; __syncthreads();
    }
    if (idx <= n) row_ptr[idx] = s[t] - v;     // local exclusive
    if (t == 255) bsum[blockIdx.x] = s[255];
}

__global__ void k_scan_b(const int* bsum, int* boff, int nb) {
    __shared__ int s[512];
    int t = threadIdx.x;
    int v = (t < nb) ? bsum[t] : 0;
    s[t] = v; __syncthreads();
    for (int off = 1; off < 512; off <<= 1) {
        int x = (t >= off) ? s[t - off] : 0;
        __syncthreads(); s[t] += x; __syncthreads();
    }
    if (t < nb) boff[t] = s[t] - v;            // exclusive block offsets
}

// single 8B store per edge: epair[pos] = {src, bits(dinv[src])}; row_ptr global = local + boff
__global__ void k_fill(const int* ei, int E, int n, const int* row_ptr, const int* boff,
                       const float* dinv, int* fill, int2* epair) {
    int i = blockIdx.x * blockDim.x + threadIdx.x;
    int total = E + n;
    if (i >= total) return;
    int u, v;
    if (i < E) { u = ei[i]; v = ei[E + i]; }
    else { u = i - E; v = u; }                 // self loop
    int p = atomicAdd(&fill[v], 1);
    int pos = row_ptr[v] + boff[v >> 8] + p;
    int2 pr; pr.x = u; pr.y = __float_as_int(dinv[u]);
    epair[pos] = pr;
}

// ---------------- compute kernels ----------------

// linb(bf16) = x(fp32) @ W1 via MFMA. Block = 4 waves, 64 rows. Layer-1 only.
__global__ __launch_bounds__(256) void k_gemm0(const float* __restrict__ A,
                                               const unsigned short* __restrict__ Wb,
                                               unsigned short* __restrict__ C, int nrows) {
    __shared__ __align__(16) unsigned short Ws[16384];   // 32 KB
    const int tid = threadIdx.x;
    for (int i = tid; i < 2048; i += 256)
        ((uint4*)Ws)[i] = ((const uint4*)Wb)[i];
    __syncthreads();

    const int wv = tid >> 6;
    const int lane = tid & 63;
    const int R0 = blockIdx.x * 64 + wv * 16;
    if (R0 >= nrows) return;
    const int m = lane & 15, q = lane >> 4;
    int rr = R0 + m; if (rr >= nrows) rr = nrows - 1;
    const float* Ar = A + (size_t)rr * DD + q * 8;

    bf16x8 af[4];
#pragma unroll
    for (int kc = 0; kc < 4; kc++) {
        float4 lo = *(const float4*)(Ar + kc * 32);
        float4 hi = *(const float4*)(Ar + kc * 32 + 4);
        unsigned short t[8];
        t[0] = f2bf(lo.x); t[1] = f2bf(lo.y); t[2] = f2bf(lo.z); t[3] = f2bf(lo.w);
        t[4] = f2bf(hi.x); t[5] = f2bf(hi.y); t[6] = f2bf(hi.z); t[7] = f2bf(hi.w);
        af[kc] = *(const bf16x8*)t;
    }

    f32x4 acc[8];
#pragma unroll
    for (int cc = 0; cc < 8; cc++) acc[cc] = (f32x4){0.f, 0.f, 0.f, 0.f};
#pragma unroll
    for (int kc = 0; kc < 4; kc++)
#pragma unroll
        for (int cc = 0; cc < 8; cc++) {
            bf16x8 b = *(const bf16x8*)&Ws[(size_t)((kc * 8 + cc) * 64 + lane) * 8];
            acc[cc] = __builtin_amdgcn_mfma_f32_16x16x32_bf16(af[kc], b, acc[cc], 0, 0, 0);
        }

#pragma unroll
    for (int cc = 0; cc < 8; cc++)
#pragma unroll
        for (int i = 0; i < 4; i++) {
            int r = R0 + q * 4 + i;
            if (r < nrows) C[(size_t)r * DD + cc * 16 + m] = f2bf(acc[cc][i]);
        }
}

// outb(bf16)[v] = bias + dv * sum_j w_j * lin_bf16[u_j]; 2 nodes/wave; unroll-4.
__global__ void k_agg(const unsigned short* __restrict__ lin, const int* __restrict__ row_ptr,
                      const int* __restrict__ boff, const long long* __restrict__ epair,
                      const float* __restrict__ dinv, const float* __restrict__ bias,
                      unsigned short* __restrict__ outb, int n) {
    int lane = threadIdx.x;
    int half = lane >> 5;
    int li = lane & 31;
    int v = blockIdx.x * 8 + threadIdx.y * 2 + half;
    if (v >= n) return;
    int c = li * 4;
    int s = row_ptr[v] + boff[v >> 8];
    int e = row_ptr[v + 1] + boff[(v + 1) >> 8];
    float dv = dinv[v];
    float4 a0 = *(const float4*)&bias[c];
    float4 a1 = make_float4(0.f, 0.f, 0.f, 0.f);
    float4 a2 = make_float4(0.f, 0.f, 0.f, 0.f);
    float4 a3 = make_float4(0.f, 0.f, 0.f, 0.f);
    int j = s;
    for (; j + 3 < e; j += 4) {
        long long q0 = __builtin_nontemporal_load(&epair[j]);
        long long q1 = __builtin_nontemporal_load(&epair[j + 1]);
        long long q2 = __builtin_nontemporal_load(&epair[j + 2]);
        long long q3 = __builtin_nontemporal_load(&epair[j + 3]);
        int u0 = (int)q0, u1 = (int)q1, u2 = (int)q2, u3 = (int)q3;
        float w0 = dv * __int_as_float((int)(q0 >> 32));
        float w1 = dv * __int_as_float((int)(q1 >> 32));
        float w2 = dv * __int_as_float((int)(q2 >> 32));
        float w3 = dv * __int_as_float((int)(q3 >> 32));
        ushort4 t0 = *(const ushort4*)&lin[(size_t)u0 * DD + c];
        ushort4 t1 = *(const ushort4*)&lin[(size_t)u1 * DD + c];
        ushort4 t2 = *(const ushort4*)&lin[(size_t)u2 * DD + c];
        ushort4 t3 = *(const ushort4*)&lin[(size_t)u3 * DD + c];
        a0.x += w0 * bf2f(t0.x); a0.y += w0 * bf2f(t0.y);
        a0.z += w0 * bf2f(t0.z); a0.w += w0 * bf2f(t0.w);
        a1.x += w1 * bf2f(t1.x); a1.y += w1 * bf2f(t1.y);
        a1.z += w1 * bf2f(t1.z); a1.w += w1 * bf2f(t1.w);
        a2.x += w2 * bf2f(t2.x); a2.y += w2 * bf2f(t2.y);
        a2.z += w2 * bf2f(t2.z); a2.w += w2 * bf2f(t2.w);
        a3.x += w3 * bf2f(t3.x); a3.y += w3 * bf2f(t3.y);
        a3.z += w3 * bf2f(t3.z); a3.w += w3 * bf2f(t3.w);
    }
    for (; j < e; ++j) {
        long long q = __builtin_nontemporal_load(&epair[j]);
        int u = (int)q;
        float w = dv * __int_as_float((int)(q >> 32));
        ushort4 t = *(const ushort4*)&lin[(size_t)u * DD + c];
        a0.x += w * bf2f(t.x); a0.y += w * bf2f(t.y);
        a0.z += w * bf2f(t.z); a0.w += w * bf2f(t.w);
    }
    a0.x += a1.x + a2.x + a3.x; a0.y += a1.y + a2.y + a3.y;
    a0.z += a1.z + a2.z + a3.z; a0.w += a1.w + a2.w + a3.w;
    ushort4 o;
    o.x = f2bf(a0.x); o.y = f2bf(a0.y); o.z = f2bf(a0.z); o.w = f2bf(a0.w);
    *(ushort4*)&outb[(size_t)v * DD + c] = o;
}

// stats[c] += col sums, stats[128+c] += col sumsq over bf16 X (LDS-reduced per block)
__global__ __launch_bounds__(256) void k_bnstats(const unsigned short* __restrict__ X, int n,
                                                 float* __restrict__ stats) {
    int cg = (threadIdx.x & 31) * 4;
    int rg = threadIdx.x >> 5;
    float s0 = 0, s1 = 0, s2 = 0, s3 = 0;
    float q0 = 0, q1 = 0, q2 = 0, q3 = 0;
    for (int r = blockIdx.x * 8 + rg; r < n; r += gridDim.x * 8) {
        ushort4 xv = *(const ushort4*)&X[(size_t)r * DD + cg];
        float x0 = bf2f(xv.x), x1 = bf2f(xv.y), x2 = bf2f(xv.z), x3 = bf2f(xv.w);
        s0 += x0; s1 += x1; s2 += x2; s3 += x3;
        q0 += x0 * x0; q1 += x1 * x1; q2 += x2 * x2; q3 += x3 * x3;
    }
    __shared__ float sh[8][128];
    __shared__ float qh[8][128];
    sh[rg][cg] = s0; sh[rg][cg + 1] = s1; sh[rg][cg + 2] = s2; sh[rg][cg + 3] = s3;
    qh[rg][cg] = q0; qh[rg][cg + 1] = q1; qh[rg][cg + 2] = q2; qh[rg][cg + 3] = q3;
    __syncthreads();
    if (threadIdx.x < 128) {
        float a = 0, b = 0;
        for (int g = 0; g < 8; g++) { a += sh[g][threadIdx.x]; b += qh[g][threadIdx.x]; }
        atomicAdd(&stats[threadIdx.x], a);
        atomicAdd(&stats[128 + threadIdx.x], b);
    }
}

// Fused: h = l2norm(relu(bn(aggX)) [+ res]);  hbf_out = bf16(h);  linb_out = h @ W.
template <bool HAS_RES>
__global__ __launch_bounds__(256) void k_fused(const unsigned short* __restrict__ aggX,
                                               const float* __restrict__ stats,
                                               const float* __restrict__ g,
                                               const float* __restrict__ be, float inv_n,
                                               const unsigned short* __restrict__ resb,
                                               const unsigned short* __restrict__ Wb,
                                               unsigned short* __restrict__ hbf_out,
                                               unsigned short* __restrict__ linb_out,
                                               int nrows) {
    __shared__ __align__(16) unsigned short Ws[16384];
    __shared__ float ssl[256];          // scale / shift
    const int tid = threadIdx.x;
    for (int i = tid; i < 2048; i += 256)
        ((uint4*)Ws)[i] = ((const uint4*)Wb)[i];
    if (tid < 128) {
        float mu = stats[tid] * inv_n;
        float var = stats[128 + tid] * inv_n - mu * mu;
        float sc = g[tid] * rsqrtf(var + BN_EPS);
        ssl[tid] = sc;
        ssl[128 + tid] = be[tid] - mu * sc;
    }
    __syncthreads();

    const int wv = tid >> 6;
    const int lane = tid & 63;
    const int R0 = blockIdx.x * 64 + wv * 16;
    if (R0 >= nrows) return;
    const int m = lane & 15, q = lane >> 4;
    int rr = R0 + m; if (rr >= nrows) rr = nrows - 1;
    const unsigned short* Ar = aggX + (size_t)rr * DD + q * 8;
    const unsigned short* Rr = HAS_RES ? resb + (size_t)rr * DD + q * 8 : nullptr;

    float y[4][8];
    float sq = 0.f;
#pragma unroll
    for (int kc = 0; kc < 4; kc++) {
        ushort4 lo = *(const ushort4*)(Ar + kc * 32);
        ushort4 hi = *(const ushort4*)(Ar + kc * 32 + 4);
        unsigned short av[8] = {lo.x, lo.y, lo.z, lo.w, hi.x, hi.y, hi.z, hi.w};
        int c0 = kc * 32 + q * 8;
        float4 sc0 = *(const float4*)&ssl[c0];
        float4 sc1 = *(const float4*)&ssl[c0 + 4];
        float4 sh0 = *(const float4*)&ssl[128 + c0];
        float4 sh1 = *(const float4*)&ssl[128 + c0 + 4];
        float scv[8] = {sc0.x, sc0.y, sc0.z, sc0.w, sc1.x, sc1.y, sc1.z, sc1.w};
        float shv[8] = {sh0.x, sh0.y, sh0.z, sh0.w, sh1.x, sh1.y, sh1.z, sh1.w};
        if (HAS_RES) {
            ushort4 rl = *(const ushort4*)(Rr + kc * 32);
            ushort4 rh = *(const ushort4*)(Rr + kc * 32 + 4);
            unsigned short rv[8] = {rl.x, rl.y, rl.z, rl.w, rh.x, rh.y, rh.z, rh.w};
#pragma unroll
            for (int j = 0; j < 8; j++) {
                float yy = fmaxf(bf2f(av[j]) * scv[j] + shv[j], 0.f) + bf2f(rv[j]);
                y[kc][j] = yy; sq += yy * yy;
            }
        } else {
#pragma unroll
            for (int j = 0; j < 8; j++) {
                float yy = fmaxf(bf2f(av[j]) * scv[j] + shv[j], 0.f);
                y[kc][j] = yy; sq += yy * yy;
            }
        }
    }
    sq += __shfl_xor(sq, 16, 64);
    sq += __shfl_xor(sq, 32, 64);
    float inv = 1.f / fmaxf(sqrtf(sq), L2_EPS);

    bf16x8 af[4];
#pragma unroll
    for (int kc = 0; kc < 4; kc++) {
        unsigned short t[8];
#pragma unroll
        for (int j = 0; j < 8; j++) t[j] = f2bf(y[kc][j] * inv);
        af[kc] = *(const bf16x8*)t;
        *(bf16x8*)&hbf_out[(size_t)rr * DD + q * 8 + kc * 32] = af[kc];
    }

    f32x4 acc[8];
#pragma unroll
    for (int cc = 0; cc < 8; cc++) acc[cc] = (f32x4){0.f, 0.f, 0.f, 0.f};
#pragma unroll
    for (int kc = 0; kc < 4; kc++)
#pragma unroll
        for (int cc = 0; cc < 8; cc++) {
            bf16x8 b = *(const bf16x8*)&Ws[(size_t)((kc * 8 + cc) * 64 + lane) * 8];
            acc[cc] = __builtin_amdgcn_mfma_f32_16x16x32_bf16(af[kc], b, acc[cc], 0, 0, 0);
        }

#pragma unroll
    for (int cc = 0; cc < 8; cc++)
#pragma unroll
        for (int i = 0; i < 4; i++) {
            int r = R0 + q * 4 + i;
            if (r < nrows) linb_out[(size_t)r * DD + cc * 16 + m] = f2bf(acc[cc][i]);
        }
}

// Fused output: h3 = l2norm(relu(bn(aggX)) + res);  out = h3 @ Wout + bout (fp32)
__global__ __launch_bounds__(256) void k_outfused(const unsigned short* __restrict__ aggX,
                                                  const float* __restrict__ stats,
                                                  const float* __restrict__ g,
                                                  const float* __restrict__ be, float inv_n,
                                                  const unsigned short* __restrict__ resb,
                                                  const unsigned short* __restrict__ wob,
                                                  const float* __restrict__ bout,
                                                  float* __restrict__ C, int nrows) {
    __shared__ __align__(16) unsigned short Ws[6144];
    __shared__ float ssl[256];
    const int tid = threadIdx.x;
    for (int i = tid; i < 768; i += 256)
        ((uint4*)Ws)[i] = ((const uint4*)wob)[i];
    if (tid < 128) {
        float mu = stats[tid] * inv_n;
        float var = stats[128 + tid] * inv_n - mu * mu;
        float sc = g[tid] * rsqrtf(var + BN_EPS);
        ssl[tid] = sc;
        ssl[128 + tid] = be[tid] - mu * sc;
    }
    __syncthreads();

    const int wv = tid >> 6;
    const int lane = tid & 63;
    const int R0 = blockIdx.x * 64 + wv * 16;
    if (R0 >= nrows) return;
    const int m = lane & 15, q = lane >> 4;
    int rr = R0 + m; if (rr >= nrows) rr = nrows - 1;
    const unsigned short* Ar = aggX + (size_t)rr * DD + q * 8;
    const unsigned short* Rr = resb + (size_t)rr * DD + q * 8;

    float y[4][8];
    float sq = 0.f;
#pragma unroll
    for (int kc = 0; kc < 4; kc++) {
        ushort4 lo = *(const ushort4*)(Ar + kc * 32);
        ushort4 hi = *(const ushort4*)(Ar + kc * 32 + 4);
        ushort4 rl = *(const ushort4*)(Rr + kc * 32);
        ushort4 rh = *(const ushort4*)(Rr + kc * 32 + 4);
        unsigned short av[8] = {lo.x, lo.y, lo.z, lo.w, hi.x, hi.y, hi.z, hi.w};
        unsigned short rv[8] = {rl.x, rl.y, rl.z, rl.w, rh.x, rh.y, rh.z, rh.w};
        int c0 = kc * 32 + q * 8;
        float4 sc0 = *(const float4*)&ssl[c0];
        float4 sc1 = *(const float4*)&ssl[c0 + 4];
        float4 sh0 = *(const float4*)&ssl[128 + c0];
        float4 sh1 = *(const float4*)&ssl[128 + c0 + 4];
        float scv[8] = {sc0.x, sc0.y, sc0.z, sc0.w, sc1.x, sc1.y, sc1.z, sc1.w};
        float shv[8] = {sh0.x, sh0.y, sh0.z, sh0.w, sh1.x, sh1.y, sh1.z, sh1.w};
#pragma unroll
        for (int j = 0; j < 8; j++) {
            float yy = fmaxf(bf2f(av[j]) * scv[j] + shv[j], 0.f) + bf2f(rv[j]);
            y[kc][j] = yy; sq += yy * yy;
        }
    }
    sq += __shfl_xor(sq, 16, 64);
    sq += __shfl_xor(sq, 32, 64);
    float inv = 1.f / fmaxf(sqrtf(sq), L2_EPS);

    bf16x8 af[4];
#pragma unroll
    for (int kc = 0; kc < 4; kc++) {
        unsigned short t[8];
#pragma unroll
        for (int j = 0; j < 8; j++) t[j] = f2bf(y[kc][j] * inv);
        af[kc] = *(const bf16x8*)t;
    }

    f32x4 acc[3];
#pragma unroll
    for (int cc = 0; cc < 3; cc++) acc[cc] = (f32x4){0.f, 0.f, 0.f, 0.f};
#pragma unroll
    for (int kc = 0; kc < 4; kc++)
#pragma unroll
        for (int cc = 0; cc < 3; cc++) {
            bf16x8 b = *(const bf16x8*)&Ws[(size_t)((kc * 3 + cc) * 64 + lane) * 8];
            acc[cc] = __builtin_amdgcn_mfma_f32_16x16x32_bf16(af[kc], b, acc[cc], 0, 0, 0);
        }

#pragma unroll
    for (int cc = 0; cc < 3; cc++) {
        int col = cc * 16 + m;
        if (col < COUT) {
            float bb = bout[col];
#pragma unroll
            for (int i = 0; i < 4; i++) {
                int r = R0 + q * 4 + i;
                if (r < nrows) C[(size_t)r * COUT + col] = acc[cc][i] + bb;
            }
        }
    }
}

// ---------------- host ----------------

extern "C" void kernel_launch(void* const* d_in, const int* in_sizes, int n_in,
                              void* d_out, int out_size, void* d_ws, size_t ws_size,
                              hipStream_t stream) {
    const float* x    = (const float*)d_in[0];
    const int*   ei   = (const int*)d_in[1];
    const float* W1   = (const float*)d_in[2];
    const float* b1   = (const float*)d_in[3];
    const float* W2   = (const float*)d_in[4];
    const float* b2   = (const float*)d_in[5];
    const float* W3   = (const float*)d_in[6];
    const float* b3   = (const float*)d_in[7];
    const float* g1   = (const float*)d_in[8];
    const float* be1  = (const float*)d_in[9];
    const float* g2   = (const float*)d_in[10];
    const float* be2  = (const float*)d_in[11];
    const float* g3   = (const float*)d_in[12];
    const float* be3  = (const float*)d_in[13];
    const float* Wout = (const float*)d_in[14];
    const float* bout = (const float*)d_in[15];
    float* out = (float*)d_out;

    const int N = in_sizes[0] / DD;
    const int E = in_sizes[1] / 2;
    const int NNZ = E + N;

    // workspace layout
    char* w = (char*)d_ws;
    unsigned short* linb = (unsigned short*)w; w += (size_t)N * DD * sizeof(unsigned short);
    unsigned short* aggA = (unsigned short*)w; w += (size_t)N * DD * sizeof(unsigned short);
    unsigned short* aggB = (unsigned short*)w; w += (size_t)N * DD * sizeof(unsigned short);
    unsigned short* hbf1 = (unsigned short*)w; w += (size_t)N * DD * sizeof(unsigned short);
    unsigned short* hbf2 = (unsigned short*)w; w += (size_t)N * DD * sizeof(unsigned short);
    unsigned short* wb   = (unsigned short*)w; w += 3 * 16384 * sizeof(unsigned short);
    unsigned short* wob  = (unsigned short*)w; w += 6144 * sizeof(unsigned short);
    int2* epair  = (int2*)w;                   w += (size_t)NNZ * sizeof(int2);
    int* deg     = (int*)w;                    w += (size_t)N * sizeof(int);   // deg+fill contiguous
    int* fill    = (int*)w;                    w += (size_t)N * sizeof(int);
    int* row_ptr = (int*)w;                    w += (size_t)(N + 1) * sizeof(int);
    float* dinv  = (float*)w;                  w += (size_t)N * sizeof(float);
    int* bsum    = (int*)w;                    w += 512 * sizeof(int);
    int* boff    = (int*)w;                    w += 512 * sizeof(int);
    float* stats = (float*)w;                  w += 768 * sizeof(float);

    const int NB = (N + 1 + 255) / 256;      // scan blocks
    const int STATS_GRID = 128;
    const int ZN = 2 * N;                    // deg+fill ints (N multiple of 4 -> ZN mult of 8)
    const int ZBLK = (ZN + 2047) / 2048;

    // ---- prep (weights repack + zero deg/fill/stats) + CSR build ----
    k_prep<<<28 + ZBLK, 256, 0, stream>>>(W1, W2, W3, Wout, wb, wob, stats, deg, ZN);
    k_hist<<<(E + 255) / 256, 256, 0, stream>>>(ei, E, deg);
    k_scan_a<<<NB, 256, 0, stream>>>(deg, row_ptr, bsum, dinv, N);
    k_scan_b<<<1, 512, 0, stream>>>(bsum, boff, NB);
    k_fill<<<(NNZ + 255) / 256, 256, 0, stream>>>(ei, E, N, row_ptr, boff, dinv, fill, epair);

    int gemmGrid = (N + 63) / 64;
    dim3 aggGrid((N + 7) / 8);
    dim3 aggBlk(64, 4);
    float inv_n = 1.0f / (float)N;

    // ---- layer 1 ----
    k_gemm0<<<gemmGrid, 256, 0, stream>>>(x, wb, linb, N);
    k_agg<<<aggGrid, aggBlk, 0, stream>>>(linb, row_ptr, boff, (const long long*)epair,
                                          dinv, b1, aggA, N);
    k_bnstats<<<STATS_GRID, 256, 0, stream>>>(aggA, N, stats);
    // ---- layer 2 (post1 fused into gemm2) ----
    k_fused<false><<<gemmGrid, 256, 0, stream>>>(aggA, stats, g1, be1, inv_n,
                                                 nullptr, wb + 16384, hbf1, linb, N);
    k_agg<<<aggGrid, aggBlk, 0, stream>>>(linb, row_ptr, boff, (const long long*)epair,
                                          dinv, b2, aggB, N);
    k_bnstats<<<STATS_GRID, 256, 0, stream>>>(aggB, N, stats + 256);
    // ---- layer 3 (post2 fused into gemm3) ----
    k_fused<true><<<gemmGrid, 256, 0, stream>>>(aggB, stats + 256, g2, be2, inv_n,
                                                hbf1, wb + 32768, hbf2, linb, N);
    k_agg<<<aggGrid, aggBlk, 0, stream>>>(linb, row_ptr, boff, (const long long*)epair,
                                          dinv, b3, aggA, N);
    k_bnstats<<<STATS_GRID, 256, 0, stream>>>(aggA, N, stats + 512);
    // ---- output (post3 fused into output GEMM) ----
    k_outfused<<<gemmGrid, 256, 0, stream>>>(aggA, stats + 512, g3, be3, inv_n,
                                             hbf2, wob, bout, out, N);
}

// Round 9
// 482.984 us; speedup vs baseline: 1.0035x; 1.0035x over previous
//
#include <hip/hip_runtime.h>
#include <math.h>

#define DD 128
#define COUT 40
#define BN_EPS 1e-5f
#define L2_EPS 1e-12f

typedef __attribute__((ext_vector_type(8))) short bf16x8;
typedef __attribute__((ext_vector_type(4))) float f32x4;

static __device__ inline unsigned short f2bf(float f) {
    unsigned int x = __float_as_uint(f);
    unsigned int r = (x + 0x7FFFu + ((x >> 16) & 1u)) >> 16;   // RNE
    return (unsigned short)r;
}
static __device__ inline float bf2f(unsigned short u) {
    return __uint_as_float(((unsigned int)u) << 16);
}

// ---------------- setup kernels ----------------

// One dispatch: repack W1/W2/W3 (blocks 0..23), Wout (24..26), zero stats (27),
// zero deg+fill (28..). W in: [k][n] fp32 row-major; out: bf16 B-fragment order.
__global__ void k_prep(const float* __restrict__ W1, const float* __restrict__ W2,
                       const float* __restrict__ W3, const float* __restrict__ Wout,
                       unsigned short* __restrict__ wb,    // 3 * 16384
                       unsigned short* __restrict__ wob,   // 6144
                       float* __restrict__ stats,          // 768
                       int* __restrict__ zbase, int zn) {  // deg+fill, zn ints (mult of 8)
    int b = blockIdx.x;
    if (b < 24) {
        int wi = b >> 3;
        const float* W = (wi == 0) ? W1 : (wi == 1) ? W2 : W3;
        unsigned short* out = wb + wi * 16384;
        int idx = (b & 7) * 256 + threadIdx.x;      // 0..2047
        int kc = idx >> 9;
        int cc = (idx >> 6) & 7;
        int lane = idx & 63;
        int n = cc * 16 + (lane & 15);
        int kb = kc * 32 + (lane >> 4) * 8;
        unsigned short tmp[8];
#pragma unroll
        for (int j = 0; j < 8; j++) tmp[j] = f2bf(W[(size_t)(kb + j) * DD + n]);
        *(uint4*)&out[(size_t)idx * 8] = *(const uint4*)tmp;
    } else if (b < 27) {
        int idx = (b - 24) * 256 + threadIdx.x;     // 0..767
        int kc = idx / 192;
        int rem = idx % 192;
        int cc = rem >> 6;
        int lane = rem & 63;
        int n = cc * 16 + (lane & 15);
        int kb = kc * 32 + (lane >> 4) * 8;
        unsigned short tmp[8];
#pragma unroll
        for (int j = 0; j < 8; j++)
            tmp[j] = (n < COUT) ? f2bf(Wout[(size_t)(kb + j) * COUT + n]) : 0;
        *(uint4*)&wob[(size_t)idx * 8] = *(const uint4*)tmp;
    } else if (b == 27) {
        stats[threadIdx.x] = 0.f;
        stats[256 + threadIdx.x] = 0.f;
        stats[512 + threadIdx.x] = 0.f;
    } else {
        int idx = (b - 28) * 2048 + threadIdx.x * 8;
        if (idx + 8 <= zn) {
            *(int4*)&zbase[idx] = make_int4(0, 0, 0, 0);
            *(int4*)&zbase[idx + 4] = make_int4(0, 0, 0, 0);
        }
    }
}

__global__ void k_hist(const int* ei, int E, int* deg) {
    int i = blockIdx.x * blockDim.x + threadIdx.x;
    if (i < E) atomicAdd(&deg[ei[E + i]], 1);   // dst = ei[E+i]
}

// scan over n+1 entries of (deg[i]+1) [0 for i==n]; also emits dinv = rsqrt(deg+1)
__global__ void k_scan_a(const int* deg, int* row_ptr, int* bsum, float* dinv, int n) {
    __shared__ int s[256];
    int t = threadIdx.x;
    int idx = blockIdx.x * 256 + t;
    int v = (idx < n) ? deg[idx] + 1 : 0;
    if (idx < n) dinv[idx] = rsqrtf((float)v);
    s[t] = v; __syncthreads();
    for (int off = 1; off < 256; off <<= 1) {
        int x = (t >= off) ? s[t - off] : 0;
        __syncthreads(); s[t] += x; __syncthreads();
    }
    if (idx <= n) row_ptr[idx] = s[t] - v;     // local exclusive
    if (t == 255) bsum[blockIdx.x] = s[255];
}

__global__ void k_scan_b(const int* bsum, int* boff, int nb) {
    __shared__ int s[512];
    int t = threadIdx.x;
    int v = (t < nb) ? bsum[t] : 0;
    s[t] = v; __syncthreads();
    for (int off = 1; off < 512; off <<= 1) {
        int x = (t >= off) ? s[t - off] : 0;
        __syncthreads(); s[t] += x; __syncthreads();
    }
    if (t < nb) boff[t] = s[t] - v;            // exclusive block offsets
}

// single 4B store per edge: colidx[pos] = src (lin rows are pre-scaled by dinv[src])
__global__ void k_fill(const int* ei, int E, int n, const int* row_ptr, const int* boff,
                       int* fill, int* colidx) {
    int i = blockIdx.x * blockDim.x + threadIdx.x;
    int total = E + n;
    if (i >= total) return;
    int u, v;
    if (i < E) { u = ei[i]; v = ei[E + i]; }
    else { u = i - E; v = u; }                 // self loop
    int p = atomicAdd(&fill[v], 1);
    int pos = row_ptr[v] + boff[v >> 8] + p;
    colidx[pos] = u;
}

// ---------------- compute kernels ----------------

// linb(bf16) = dinv_row * (x(fp32) @ W1) via MFMA. Block = 4 waves, 64 rows.
__global__ __launch_bounds__(256) void k_gemm0(const float* __restrict__ A,
                                               const unsigned short* __restrict__ Wb,
                                               const float* __restrict__ dinv,
                                               unsigned short* __restrict__ C, int nrows) {
    __shared__ __align__(16) unsigned short Ws[16384];   // 32 KB
    const int tid = threadIdx.x;
    for (int i = tid; i < 2048; i += 256)
        ((uint4*)Ws)[i] = ((const uint4*)Wb)[i];
    __syncthreads();

    const int wv = tid >> 6;
    const int lane = tid & 63;
    const int R0 = blockIdx.x * 64 + wv * 16;
    if (R0 >= nrows) return;
    const int m = lane & 15, q = lane >> 4;
    int rr = R0 + m; if (rr >= nrows) rr = nrows - 1;
    const float* Ar = A + (size_t)rr * DD + q * 8;

    bf16x8 af[4];
#pragma unroll
    for (int kc = 0; kc < 4; kc++) {
        float4 lo = *(const float4*)(Ar + kc * 32);
        float4 hi = *(const float4*)(Ar + kc * 32 + 4);
        unsigned short t[8];
        t[0] = f2bf(lo.x); t[1] = f2bf(lo.y); t[2] = f2bf(lo.z); t[3] = f2bf(lo.w);
        t[4] = f2bf(hi.x); t[5] = f2bf(hi.y); t[6] = f2bf(hi.z); t[7] = f2bf(hi.w);
        af[kc] = *(const bf16x8*)t;
    }

    f32x4 acc[8];
#pragma unroll
    for (int cc = 0; cc < 8; cc++) acc[cc] = (f32x4){0.f, 0.f, 0.f, 0.f};
#pragma unroll
    for (int kc = 0; kc < 4; kc++)
#pragma unroll
        for (int cc = 0; cc < 8; cc++) {
            bf16x8 b = *(const bf16x8*)&Ws[(size_t)((kc * 8 + cc) * 64 + lane) * 8];
            acc[cc] = __builtin_amdgcn_mfma_f32_16x16x32_bf16(af[kc], b, acc[cc], 0, 0, 0);
        }

    float dr[4];
#pragma unroll
    for (int i = 0; i < 4; i++) {
        int r = R0 + q * 4 + i;
        dr[i] = (r < nrows) ? dinv[r] : 0.f;
    }
#pragma unroll
    for (int cc = 0; cc < 8; cc++)
#pragma unroll
        for (int i = 0; i < 4; i++) {
            int r = R0 + q * 4 + i;
            if (r < nrows) C[(size_t)r * DD + cc * 16 + m] = f2bf(acc[cc][i] * dr[i]);
        }
}

// outb(bf16)[v] = bias + dv * sum_j lin'[u_j]; 2 nodes/wave; unroll-4 plain loads.
__global__ void k_agg(const unsigned short* __restrict__ lin, const int* __restrict__ row_ptr,
                      const int* __restrict__ boff, const int* __restrict__ colidx,
                      const float* __restrict__ dinv, const float* __restrict__ bias,
                      unsigned short* __restrict__ outb, int n) {
    int lane = threadIdx.x;
    int half = lane >> 5;
    int li = lane & 31;
    int v = blockIdx.x * 8 + threadIdx.y * 2 + half;
    if (v >= n) return;
    int c = li * 4;
    int s = row_ptr[v] + boff[v >> 8];
    int e = row_ptr[v + 1] + boff[(v + 1) >> 8];
    float dv = dinv[v];
    float4 a0 = make_float4(0.f, 0.f, 0.f, 0.f);
    float4 a1 = make_float4(0.f, 0.f, 0.f, 0.f);
    float4 a2 = make_float4(0.f, 0.f, 0.f, 0.f);
    float4 a3 = make_float4(0.f, 0.f, 0.f, 0.f);
    int j = s;
    for (; j + 3 < e; j += 4) {
        int u0 = colidx[j], u1 = colidx[j + 1], u2 = colidx[j + 2], u3 = colidx[j + 3];
        ushort4 t0 = *(const ushort4*)&lin[(size_t)u0 * DD + c];
        ushort4 t1 = *(const ushort4*)&lin[(size_t)u1 * DD + c];
        ushort4 t2 = *(const ushort4*)&lin[(size_t)u2 * DD + c];
        ushort4 t3 = *(const ushort4*)&lin[(size_t)u3 * DD + c];
        a0.x += bf2f(t0.x); a0.y += bf2f(t0.y); a0.z += bf2f(t0.z); a0.w += bf2f(t0.w);
        a1.x += bf2f(t1.x); a1.y += bf2f(t1.y); a1.z += bf2f(t1.z); a1.w += bf2f(t1.w);
        a2.x += bf2f(t2.x); a2.y += bf2f(t2.y); a2.z += bf2f(t2.z); a2.w += bf2f(t2.w);
        a3.x += bf2f(t3.x); a3.y += bf2f(t3.y); a3.z += bf2f(t3.z); a3.w += bf2f(t3.w);
    }
    for (; j < e; ++j) {
        int u = colidx[j];
        ushort4 t = *(const ushort4*)&lin[(size_t)u * DD + c];
        a0.x += bf2f(t.x); a0.y += bf2f(t.y); a0.z += bf2f(t.z); a0.w += bf2f(t.w);
    }
    float4 bi = *(const float4*)&bias[c];
    float ox = bi.x + dv * (a0.x + a1.x + a2.x + a3.x);
    float oy = bi.y + dv * (a0.y + a1.y + a2.y + a3.y);
    float oz = bi.z + dv * (a0.z + a1.z + a2.z + a3.z);
    float ow = bi.w + dv * (a0.w + a1.w + a2.w + a3.w);
    ushort4 o;
    o.x = f2bf(ox); o.y = f2bf(oy); o.z = f2bf(oz); o.w = f2bf(ow);
    *(ushort4*)&outb[(size_t)v * DD + c] = o;
}

// stats[c] += col sums, stats[128+c] += col sumsq over bf16 X (LDS-reduced per block)
__global__ __launch_bounds__(256) void k_bnstats(const unsigned short* __restrict__ X, int n,
                                                 float* __restrict__ stats) {
    int cg = (threadIdx.x & 31) * 4;
    int rg = threadIdx.x >> 5;
    float s0 = 0, s1 = 0, s2 = 0, s3 = 0;
    float q0 = 0, q1 = 0, q2 = 0, q3 = 0;
    for (int r = blockIdx.x * 8 + rg; r < n; r += gridDim.x * 8) {
        ushort4 xv = *(const ushort4*)&X[(size_t)r * DD + cg];
        float x0 = bf2f(xv.x), x1 = bf2f(xv.y), x2 = bf2f(xv.z), x3 = bf2f(xv.w);
        s0 += x0; s1 += x1; s2 += x2; s3 += x3;
        q0 += x0 * x0; q1 += x1 * x1; q2 += x2 * x2; q3 += x3 * x3;
    }
    __shared__ float sh[8][128];
    __shared__ float qh[8][128];
    sh[rg][cg] = s0; sh[rg][cg + 1] = s1; sh[rg][cg + 2] = s2; sh[rg][cg + 3] = s3;
    qh[rg][cg] = q0; qh[rg][cg + 1] = q1; qh[rg][cg + 2] = q2; qh[rg][cg + 3] = q3;
    __syncthreads();
    if (threadIdx.x < 128) {
        float a = 0, b = 0;
        for (int g = 0; g < 8; g++) { a += sh[g][threadIdx.x]; b += qh[g][threadIdx.x]; }
        atomicAdd(&stats[threadIdx.x], a);
        atomicAdd(&stats[128 + threadIdx.x], b);
    }
}

// Fused: h = l2norm(relu(bn(aggX)) [+ res]);  hbf_out = bf16(h);
// linb_out = dinv_row * (h @ W)   (pre-scaled for the gather).
template <bool HAS_RES>
__global__ __launch_bounds__(256) void k_fused(const unsigned short* __restrict__ aggX,
                                               const float* __restrict__ stats,
                                               const float* __restrict__ g,
                                               const float* __restrict__ be, float inv_n,
                                               const unsigned short* __restrict__ resb,
                                               const unsigned short* __restrict__ Wb,
                                               const float* __restrict__ dinv,
                                               unsigned short* __restrict__ hbf_out,
                                               unsigned short* __restrict__ linb_out,
                                               int nrows) {
    __shared__ __align__(16) unsigned short Ws[16384];
    __shared__ float ssl[256];          // scale / shift
    const int tid = threadIdx.x;
    for (int i = tid; i < 2048; i += 256)
        ((uint4*)Ws)[i] = ((const uint4*)Wb)[i];
    if (tid < 128) {
        float mu = stats[tid] * inv_n;
        float var = stats[128 + tid] * inv_n - mu * mu;
        float sc = g[tid] * rsqrtf(var + BN_EPS);
        ssl[tid] = sc;
        ssl[128 + tid] = be[tid] - mu * sc;
    }
    __syncthreads();

    const int wv = tid >> 6;
    const int lane = tid & 63;
    const int R0 = blockIdx.x * 64 + wv * 16;
    if (R0 >= nrows) return;
    const int m = lane & 15, q = lane >> 4;
    int rr = R0 + m; if (rr >= nrows) rr = nrows - 1;
    const unsigned short* Ar = aggX + (size_t)rr * DD + q * 8;
    const unsigned short* Rr = HAS_RES ? resb + (size_t)rr * DD + q * 8 : nullptr;

    float y[4][8];
    float sq = 0.f;
#pragma unroll
    for (int kc = 0; kc < 4; kc++) {
        ushort4 lo = *(const ushort4*)(Ar + kc * 32);
        ushort4 hi = *(const ushort4*)(Ar + kc * 32 + 4);
        unsigned short av[8] = {lo.x, lo.y, lo.z, lo.w, hi.x, hi.y, hi.z, hi.w};
        int c0 = kc * 32 + q * 8;
        float4 sc0 = *(const float4*)&ssl[c0];
        float4 sc1 = *(const float4*)&ssl[c0 + 4];
        float4 sh0 = *(const float4*)&ssl[128 + c0];
        float4 sh1 = *(const float4*)&ssl[128 + c0 + 4];
        float scv[8] = {sc0.x, sc0.y, sc0.z, sc0.w, sc1.x, sc1.y, sc1.z, sc1.w};
        float shv[8] = {sh0.x, sh0.y, sh0.z, sh0.w, sh1.x, sh1.y, sh1.z, sh1.w};
        if (HAS_RES) {
            ushort4 rl = *(const ushort4*)(Rr + kc * 32);
            ushort4 rh = *(const ushort4*)(Rr + kc * 32 + 4);
            unsigned short rv[8] = {rl.x, rl.y, rl.z, rl.w, rh.x, rh.y, rh.z, rh.w};
#pragma unroll
            for (int j = 0; j < 8; j++) {
                float yy = fmaxf(bf2f(av[j]) * scv[j] + shv[j], 0.f) + bf2f(rv[j]);
                y[kc][j] = yy; sq += yy * yy;
            }
        } else {
#pragma unroll
            for (int j = 0; j < 8; j++) {
                float yy = fmaxf(bf2f(av[j]) * scv[j] + shv[j], 0.f);
                y[kc][j] = yy; sq += yy * yy;
            }
        }
    }
    sq += __shfl_xor(sq, 16, 64);
    sq += __shfl_xor(sq, 32, 64);
    float inv = 1.f / fmaxf(sqrtf(sq), L2_EPS);

    bf16x8 af[4];
#pragma unroll
    for (int kc = 0; kc < 4; kc++) {
        unsigned short t[8];
#pragma unroll
        for (int j = 0; j < 8; j++) t[j] = f2bf(y[kc][j] * inv);
        af[kc] = *(const bf16x8*)t;
        *(bf16x8*)&hbf_out[(size_t)rr * DD + q * 8 + kc * 32] = af[kc];
    }

    f32x4 acc[8];
#pragma unroll
    for (int cc = 0; cc < 8; cc++) acc[cc] = (f32x4){0.f, 0.f, 0.f, 0.f};
#pragma unroll
    for (int kc = 0; kc < 4; kc++)
#pragma unroll
        for (int cc = 0; cc < 8; cc++) {
            bf16x8 b = *(const bf16x8*)&Ws[(size_t)((kc * 8 + cc) * 64 + lane) * 8];
            acc[cc] = __builtin_amdgcn_mfma_f32_16x16x32_bf16(af[kc], b, acc[cc], 0, 0, 0);
        }

    float dr[4];
#pragma unroll
    for (int i = 0; i < 4; i++) {
        int r = R0 + q * 4 + i;
        dr[i] = (r < nrows) ? dinv[r] : 0.f;
    }
#pragma unroll
    for (int cc = 0; cc < 8; cc++)
#pragma unroll
        for (int i = 0; i < 4; i++) {
            int r = R0 + q * 4 + i;
            if (r < nrows) linb_out[(size_t)r * DD + cc * 16 + m] = f2bf(acc[cc][i] * dr[i]);
        }
}

// Fused output: h3 = l2norm(relu(bn(aggX)) + res);  out = h3 @ Wout + bout (fp32)
__global__ __launch_bounds__(256) void k_outfused(const unsigned short* __restrict__ aggX,
                                                  const float* __restrict__ stats,
                                                  const float* __restrict__ g,
                                                  const float* __restrict__ be, float inv_n,
                                                  const unsigned short* __restrict__ resb,
                                                  const unsigned short* __restrict__ wob,
                                                  const float* __restrict__ bout,
                                                  float* __restrict__ C, int nrows) {
    __shared__ __align__(16) unsigned short Ws[6144];
    __shared__ float ssl[256];
    const int tid = threadIdx.x;
    for (int i = tid; i < 768; i += 256)
        ((uint4*)Ws)[i] = ((const uint4*)wob)[i];
    if (tid < 128) {
        float mu = stats[tid] * inv_n;
        float var = stats[128 + tid] * inv_n - mu * mu;
        float sc = g[tid] * rsqrtf(var + BN_EPS);
        ssl[tid] = sc;
        ssl[128 + tid] = be[tid] - mu * sc;
    }
    __syncthreads();

    const int wv = tid >> 6;
    const int lane = tid & 63;
    const int R0 = blockIdx.x * 64 + wv * 16;
    if (R0 >= nrows) return;
    const int m = lane & 15, q = lane >> 4;
    int rr = R0 + m; if (rr >= nrows) rr = nrows - 1;
    const unsigned short* Ar = aggX + (size_t)rr * DD + q * 8;
    const unsigned short* Rr = resb + (size_t)rr * DD + q * 8;

    float y[4][8];
    float sq = 0.f;
#pragma unroll
    for (int kc = 0; kc < 4; kc++) {
        ushort4 lo = *(const ushort4*)(Ar + kc * 32);
        ushort4 hi = *(const ushort4*)(Ar + kc * 32 + 4);
        ushort4 rl = *(const ushort4*)(Rr + kc * 32);
        ushort4 rh = *(const ushort4*)(Rr + kc * 32 + 4);
        unsigned short av[8] = {lo.x, lo.y, lo.z, lo.w, hi.x, hi.y, hi.z, hi.w};
        unsigned short rv[8] = {rl.x, rl.y, rl.z, rl.w, rh.x, rh.y, rh.z, rh.w};
        int c0 = kc * 32 + q * 8;
        float4 sc0 = *(const float4*)&ssl[c0];
        float4 sc1 = *(const float4*)&ssl[c0 + 4];
        float4 sh0 = *(const float4*)&ssl[128 + c0];
        float4 sh1 = *(const float4*)&ssl[128 + c0 + 4];
        float scv[8] = {sc0.x, sc0.y, sc0.z, sc0.w, sc1.x, sc1.y, sc1.z, sc1.w};
        float shv[8] = {sh0.x, sh0.y, sh0.z, sh0.w, sh1.x, sh1.y, sh1.z, sh1.w};
#pragma unroll
        for (int j = 0; j < 8; j++) {
            float yy = fmaxf(bf2f(av[j]) * scv[j] + shv[j], 0.f) + bf2f(rv[j]);
            y[kc][j] = yy; sq += yy * yy;
        }
    }
    sq += __shfl_xor(sq, 16, 64);
    sq += __shfl_xor(sq, 32, 64);
    float inv = 1.f / fmaxf(sqrtf(sq), L2_EPS);

    bf16x8 af[4];
#pragma unroll
    for (int kc = 0; kc < 4; kc++) {
        unsigned short t[8];
#pragma unroll
        for (int j = 0; j < 8; j++) t[j] = f2bf(y[kc][j] * inv);
        af[kc] = *(const bf16x8*)t;
    }

    f32x4 acc[3];
#pragma unroll
    for (int cc = 0; cc < 3; cc++) acc[cc] = (f32x4){0.f, 0.f, 0.f, 0.f};
#pragma unroll
    for (int kc = 0; kc < 4; kc++)
#pragma unroll
        for (int cc = 0; cc < 3; cc++) {
            bf16x8 b = *(const bf16x8*)&Ws[(size_t)((kc * 3 + cc) * 64 + lane) * 8];
            acc[cc] = __builtin_amdgcn_mfma_f32_16x16x32_bf16(af[kc], b, acc[cc], 0, 0, 0);
        }

#pragma unroll
    for (int cc = 0; cc < 3; cc++) {
        int col = cc * 16 + m;
        if (col < COUT) {
            float bb = bout[col];
#pragma unroll
            for (int i = 0; i < 4; i++) {
                int r = R0 + q * 4 + i;
                if (r < nrows) C[(size_t)r * COUT + col] = acc[cc][i] + bb;
            }
        }
    }
}

// ---------------- host ----------------

extern "C" void kernel_launch(void* const* d_in, const int* in_sizes, int n_in,
                              void* d_out, int out_size, void* d_ws, size_t ws_size,
                              hipStream_t stream) {
    const float* x    = (const float*)d_in[0];
    const int*   ei   = (const int*)d_in[1];
    const float* W1   = (const float*)d_in[2];
    const float* b1   = (const float*)d_in[3];
    const float* W2   = (const float*)d_in[4];
    const float* b2   = (const float*)d_in[5];
    const float* W3   = (const float*)d_in[6];
    const float* b3   = (const float*)d_in[7];
    const float* g1   = (const float*)d_in[8];
    const float* be1  = (const float*)d_in[9];
    const float* g2   = (const float*)d_in[10];
    const float* be2  = (const float*)d_in[11];
    const float* g3   = (const float*)d_in[12];
    const float* be3  = (const float*)d_in[13];
    const float* Wout = (const float*)d_in[14];
    const float* bout = (const float*)d_in[15];
    float* out = (float*)d_out;

    const int N = in_sizes[0] / DD;
    const int E = in_sizes[1] / 2;
    const int NNZ = E + N;

    // workspace layout
    char* w = (char*)d_ws;
    unsigned short* linb = (unsigned short*)w; w += (size_t)N * DD * sizeof(unsigned short);
    unsigned short* aggA = (unsigned short*)w; w += (size_t)N * DD * sizeof(unsigned short);
    unsigned short* aggB = (unsigned short*)w; w += (size_t)N * DD * sizeof(unsigned short);
    unsigned short* hbf1 = (unsigned short*)w; w += (size_t)N * DD * sizeof(unsigned short);
    unsigned short* hbf2 = (unsigned short*)w; w += (size_t)N * DD * sizeof(unsigned short);
    unsigned short* wb   = (unsigned short*)w; w += 3 * 16384 * sizeof(unsigned short);
    unsigned short* wob  = (unsigned short*)w; w += 6144 * sizeof(unsigned short);
    int* colidx  = (int*)w;                    w += (size_t)NNZ * sizeof(int);
    int* deg     = (int*)w;                    w += (size_t)N * sizeof(int);   // deg+fill contiguous
    int* fill    = (int*)w;                    w += (size_t)N * sizeof(int);
    int* row_ptr = (int*)w;                    w += (size_t)(N + 1) * sizeof(int);
    float* dinv  = (float*)w;                  w += (size_t)N * sizeof(float);
    int* bsum    = (int*)w;                    w += 512 * sizeof(int);
    int* boff    = (int*)w;                    w += 512 * sizeof(int);
    float* stats = (float*)w;                  w += 768 * sizeof(float);

    const int NB = (N + 1 + 255) / 256;      // scan blocks
    const int STATS_GRID = 128;
    const int ZN = 2 * N;                    // deg+fill ints
    const int ZBLK = (ZN + 2047) / 2048;

    // ---- prep (weights repack + zero deg/fill/stats) + CSR build ----
    k_prep<<<28 + ZBLK, 256, 0, stream>>>(W1, W2, W3, Wout, wb, wob, stats, deg, ZN);
    k_hist<<<(E + 255) / 256, 256, 0, stream>>>(ei, E, deg);
    k_scan_a<<<NB, 256, 0, stream>>>(deg, row_ptr, bsum, dinv, N);
    k_scan_b<<<1, 512, 0, stream>>>(bsum, boff, NB);
    k_fill<<<(NNZ + 255) / 256, 256, 0, stream>>>(ei, E, N, row_ptr, boff, fill, colidx);

    int gemmGrid = (N + 63) / 64;
    dim3 aggGrid((N + 7) / 8);
    dim3 aggBlk(64, 4);
    float inv_n = 1.0f / (float)N;

    // ---- layer 1 ----
    k_gemm0<<<gemmGrid, 256, 0, stream>>>(x, wb, dinv, linb, N);
    k_agg<<<aggGrid, aggBlk, 0, stream>>>(linb, row_ptr, boff, colidx, dinv, b1, aggA, N);
    k_bnstats<<<STATS_GRID, 256, 0, stream>>>(aggA, N, stats);
    // ---- layer 2 (post1 fused into gemm2) ----
    k_fused<false><<<gemmGrid, 256, 0, stream>>>(aggA, stats, g1, be1, inv_n,
                                                 nullptr, wb + 16384, dinv, hbf1, linb, N);
    k_agg<<<aggGrid, aggBlk, 0, stream>>>(linb, row_ptr, boff, colidx, dinv, b2, aggB, N);
    k_bnstats<<<STATS_GRID, 256, 0, stream>>>(aggB, N, stats + 256);
    // ---- layer 3 (post2 fused into gemm3) ----
    k_fused<true><<<gemmGrid, 256, 0, stream>>>(aggB, stats + 256, g2, be2, inv_n,
                                                hbf1, wb + 32768, dinv, hbf2, linb, N);
    k_agg<<<aggGrid, aggBlk, 0, stream>>>(linb, row_ptr, boff, colidx, dinv, b3, aggA, N);
    k_bnstats<<<STATS_GRID, 256, 0, stream>>>(aggA, N, stats + 512);
    // ---- output (post3 fused into output GEMM) ----
    k_outfused<<<gemmGrid, 256, 0, stream>>>(aggA, stats + 512, g3, be3, inv_n,
                                             hbf2, wob, bout, out, N);
}